// Round 17
// baseline (336.811 us; speedup 1.0000x reference)
//
#include <hip/hip_runtime.h>
#include <hip/hip_bf16.h>
#include <math.h>
#include <stdint.h>

#define N_NODES 50000
#define N_PAD   50048   // padded rows for MFMA tile overrun
#define N_EDGES 800000
#define N_GRAPHS 256
#define F_IN 64
#define F_HID 128
#define N_HID 512
#define N_OUT 256
#define CSR_CAP (N_EDGES + 8 * N_NODES)   // aligned-start padding headroom

#define SCAN_B 256
#define SCAN_NBLK ((N_NODES + SCAN_B - 1) / SCAN_B)   // 196

using bf16x8 = __attribute__((ext_vector_type(8))) short;   // MFMA A/B frag (4 VGPRs)
using f32x4  = __attribute__((ext_vector_type(4))) float;   // MFMA C/D frag

// pack two fp32 into a uint holding two bf16 (RNE); low16 = a, high16 = b
__device__ __forceinline__ unsigned int bf16pair(float a, float b) {
    unsigned int ua = __float_as_uint(a);
    unsigned int ub = __float_as_uint(b);
    ua += 0x7fffu + ((ua >> 16) & 1u);
    ub += 0x7fffu + ((ub >> 16) & 1u);
    return (ua >> 16) | (ub & 0xffff0000u);
}
__device__ __forceinline__ float bf16lo(unsigned int u) { return __uint_as_float(u << 16); }
__device__ __forceinline__ float bf16hi(unsigned int u) { return __uint_as_float(u & 0xffff0000u); }

// ---------------------------------------------------------------------------
// K0: xb'[s] = bf16(dis[s] * x[s])  (pre-scaled gather table)
__global__ void cvt_bf16(const float* __restrict__ in, const float* __restrict__ dis,
                         unsigned int* __restrict__ out, int n4) {
    int idx = blockIdx.x * blockDim.x + threadIdx.x;
    if (idx < n4) {
        int node = idx >> 4;                  // 16 float4 per 64-f row
        float d = dis[node];
        float4 v = ((const float4*)in)[idx];
        ((uint2*)out)[idx] = make_uint2(bf16pair(d * v.x, d * v.y),
                                        bf16pair(d * v.z, d * v.w));
    }
}

// K0b: both weight tables fp32 [K][128] -> bf16 [128][K] in one dispatch
__global__ void cvt_wt2(const float* __restrict__ W0, unsigned short* __restrict__ W0Tb,
                        const float* __restrict__ W1, unsigned short* __restrict__ W1Tb) {
    int idx = blockIdx.x * blockDim.x + threadIdx.x;
    const int N0 = F_IN * 128;
    const int N1 = F_HID * 128;
    if (idx < N0) {
        int k = idx >> 7, n = idx & 127;
        unsigned int u = __float_as_uint(W0[idx]);
        u += 0x7fffu + ((u >> 16) & 1u);
        W0Tb[n * F_IN + k] = (unsigned short)(u >> 16);
    } else if (idx < N0 + N1) {
        int j = idx - N0;
        int k = j >> 7, n = j & 127;
        unsigned int u = __float_as_uint(W1[j]);
        u += 0x7fffu + ((u >> 16) & 1u);
        W1Tb[n * F_HID + k] = (unsigned short)(u >> 16);
    }
}

// ---------------------------------------------------------------------------
// K1: in-degree count
__global__ void count_deg(const int* __restrict__ ei, int* __restrict__ indeg) {
    int e = blockIdx.x * blockDim.x + threadIdx.x;
    if (e < N_EDGES) atomicAdd(&indeg[ei[N_EDGES + e]], 1);
}

// K2a/K2b/K2c: hierarchical scan over ALIGNED degrees (alignUp(deg,8)) so each
// node's CSR segment starts 16B-aligned (enables uint4 csr loads in gathers).
__global__ __launch_bounds__(SCAN_B) void scan_partial(const int* __restrict__ indeg,
                                                       int* __restrict__ blockSums) {
    __shared__ int sdata[SCAN_B];
    int i = blockIdx.x * SCAN_B + threadIdx.x;
    int v = (i < N_NODES) ? indeg[i] : 0;
    sdata[threadIdx.x] = (v + 7) & ~7;
    __syncthreads();
    for (int off = SCAN_B / 2; off > 0; off >>= 1) {
        if (threadIdx.x < off) sdata[threadIdx.x] += sdata[threadIdx.x + off];
        __syncthreads();
    }
    if (threadIdx.x == 0) blockSums[blockIdx.x] = sdata[0];
}

__global__ __launch_bounds__(SCAN_B) void scan_block_sums(int* __restrict__ blockSums) {
    __shared__ int buf[SCAN_B];
    int tid = threadIdx.x;
    int v = (tid < SCAN_NBLK) ? blockSums[tid] : 0;
    buf[tid] = v;
    __syncthreads();
    for (int off = 1; off < SCAN_B; off <<= 1) {
        int t = (tid >= off) ? buf[tid - off] : 0;
        __syncthreads();
        buf[tid] += t;
        __syncthreads();
    }
    if (tid < SCAN_NBLK) blockSums[tid] = buf[tid] - v;   // exclusive
}

__global__ __launch_bounds__(SCAN_B) void scan_final(const int* __restrict__ indeg,
                                                     const int* __restrict__ blockSums,
                                                     int* __restrict__ offsets,
                                                     int* __restrict__ degs,
                                                     float* __restrict__ dis) {
    __shared__ int buf[SCAN_B];
    int tid = threadIdx.x;
    int i = blockIdx.x * SCAN_B + tid;
    int v = (i < N_NODES) ? indeg[i] : 0;
    if (i < N_NODES) {
        dis[i] = rsqrtf((float)(v + 1));
        degs[i] = v;
    }
    int va = (v + 7) & ~7;
    buf[tid] = va;
    __syncthreads();
    for (int off = 1; off < SCAN_B; off <<= 1) {
        int t = (tid >= off) ? buf[tid - off] : 0;
        __syncthreads();
        buf[tid] += t;
        __syncthreads();
    }
    if (i < N_NODES) offsets[i] = blockSums[blockIdx.x] + buf[tid] - va;
}

// K3: scatter edges into CSR (by dst). ushort src entries; indeg doubles as
// the cursor via atomicSub (indeg is dead after scan_final).
__global__ void build_csr(const int* __restrict__ ei, const int* __restrict__ offsets,
                          int* __restrict__ indeg, unsigned short* __restrict__ csr) {
    int e = blockIdx.x * blockDim.x + threadIdx.x;
    if (e < N_EDGES) {
        int s = ei[e];
        int d = ei[N_EDGES + e];
        int pos = atomicSub(&indeg[d], 1) - 1;   // deg-1 .. 0
        csr[offsets[d] + pos] = (unsigned short)s;
    }
}

// ---------------------------------------------------------------------------
// K4: MFMA GEMM. C[M,128] = A[M,K]@W[K,128], A bf16 [M][K], WT bf16 [128][K].
template <int K, bool BIASRELU, bool DISSCALE>
__global__ __launch_bounds__(256) void gemm_mfma(const unsigned short* __restrict__ Ab,
                                                 const unsigned short* __restrict__ WTb,
                                                 const float* __restrict__ bias,
                                                 const float* __restrict__ disv,
                                                 unsigned int* __restrict__ outb, int M) {
    int wv = threadIdx.x >> 6;
    int lane = threadIdx.x & 63;
    int m = lane & 15;
    int quad = lane >> 4;
    int row0 = blockIdx.x * 64 + wv * 16;
    f32x4 acc[8];
#pragma unroll
    for (int t = 0; t < 8; ++t) acc[t] = (f32x4){0.f, 0.f, 0.f, 0.f};
#pragma unroll
    for (int ks = 0; ks < K; ks += 32) {
        bf16x8 af = *(const bf16x8*)&Ab[(size_t)(row0 + m) * K + ks + quad * 8];
#pragma unroll
        for (int t = 0; t < 8; ++t) {
            bf16x8 bf = *(const bf16x8*)&WTb[(size_t)(t * 16 + m) * K + ks + quad * 8];
            acc[t] = __builtin_amdgcn_mfma_f32_16x16x32_bf16(af, bf, acc[t], 0, 0, 0);
        }
    }
    float dr[4];
#pragma unroll
    for (int r = 0; r < 4; ++r) {
        int row = row0 + quad * 4 + r;
        dr[r] = DISSCALE ? ((row < M) ? disv[row] : 0.f) : 1.f;
    }
#pragma unroll
    for (int t = 0; t < 8; ++t) {
        int col = t * 16 + m;
        float bcol = 0.f;
        if (BIASRELU) bcol = bias[col];
#pragma unroll
        for (int r = 0; r < 4; ++r) {
            float v = acc[t][r];
            if (BIASRELU) v = fmaxf(v + bcol, 0.f);
            if (DISSCALE) v = v * dr[r];
            float vn = __shfl_xor(v, 1, 64);    // neighbor col's value
            if ((m & 1) == 0) {
                int row = row0 + quad * 4 + r;
                if (row < M)
                    outb[(size_t)row * 64 + (col >> 1)] = bf16pair(v, vn);
            }
        }
    }
}

// ---------------------------------------------------------------------------
// K5a: F=128 aggregate over PRE-SCALED bf16 table. uint2 lanes, 2 edges/inst.
// Block-contiguous edge split: sub-half covers edges [j+8sub, j+8sub+8) ->
// ONE uint4 csr load per chunk instead of 8 scalar ushort loads.
template <bool RELU, bool BIAS, bool SCALEOUT>
__global__ __launch_bounds__(256) void aggregate128b(const uint2* __restrict__ hb2,
                                                     const int* __restrict__ offsets,
                                                     const int* __restrict__ degs,
                                                     const unsigned short* __restrict__ csr,
                                                     const float* __restrict__ dis,
                                                     const float* __restrict__ bias,
                                                     unsigned int* __restrict__ outb) {
    int wave = threadIdx.x >> 6;
    int lane = threadIdx.x & 63;
    int i = blockIdx.x * 4 + wave;
    if (i >= N_NODES) return;
    int sub = lane >> 5;
    int q   = lane & 31;
    float a0 = 0.f, a1 = 0.f, a2 = 0.f, a3 = 0.f;
    int j = offsets[i];
    int s1 = j + degs[i];
    for (; j + 16 <= s1; j += 16) {       // full chunks: one uint4 csr load
        uint4 w = *(const uint4*)&csr[j + 8 * sub];
        int s[8];
        s[0] = w.x & 0xffff;  s[1] = w.x >> 16;
        s[2] = w.y & 0xffff;  s[3] = w.y >> 16;
        s[4] = w.z & 0xffff;  s[5] = w.z >> 16;
        s[6] = w.w & 0xffff;  s[7] = w.w >> 16;
        uint2 r[8];
#pragma unroll
        for (int u = 0; u < 8; ++u) r[u] = hb2[(size_t)s[u] * 32 + q];
#pragma unroll
        for (int u = 0; u < 8; ++u) {
            a0 += bf16lo(r[u].x);  a1 += bf16hi(r[u].x);
            a2 += bf16lo(r[u].y);  a3 += bf16hi(r[u].y);
        }
    }
    if (j < s1) {                          // masked tail chunk (scalar loads)
        int s[8]; float m[8];
#pragma unroll
        for (int u = 0; u < 8; ++u) {
            int e = j + 2 * u + sub;
            bool valid = e < s1;
            s[u] = valid ? (int)csr[e] : 0;
            m[u] = valid ? 1.f : 0.f;
        }
        uint2 r[8];
#pragma unroll
        for (int u = 0; u < 8; ++u) r[u] = hb2[(size_t)s[u] * 32 + q];
#pragma unroll
        for (int u = 0; u < 8; ++u) {
            a0 += m[u] * bf16lo(r[u].x);  a1 += m[u] * bf16hi(r[u].x);
            a2 += m[u] * bf16lo(r[u].y);  a3 += m[u] * bf16hi(r[u].y);
        }
    }
    a0 += __shfl_xor(a0, 32, 64);
    a1 += __shfl_xor(a1, 32, 64);
    a2 += __shfl_xor(a2, 32, 64);
    a3 += __shfl_xor(a3, 32, 64);
    uint2 su = hb2[(size_t)i * 32 + q];     // self: weight 1 in scaled domain
    a0 += bf16lo(su.x);  a1 += bf16hi(su.x);
    a2 += bf16lo(su.y);  a3 += bf16hi(su.y);
    float dii = dis[i];
    a0 *= dii; a1 *= dii; a2 *= dii; a3 *= dii;
    if (BIAS) {
        float4 b = ((const float4*)bias)[q];
        a0 += b.x; a1 += b.y; a2 += b.z; a3 += b.w;
    }
    if (RELU) {
        a0 = fmaxf(a0, 0.f); a1 = fmaxf(a1, 0.f);
        a2 = fmaxf(a2, 0.f); a3 = fmaxf(a3, 0.f);
    }
    if (sub == 0) {
        float sc = SCALEOUT ? dii : 1.f;
        ((uint2*)outb)[(size_t)i * 32 + q] =
            make_uint2(bf16pair(sc * a0, sc * a1), bf16pair(sc * a2, sc * a3));
    }
}

// K5b: F=64 aggregate over pre-scaled bf16 x-table. uint2 lanes, 4 edges/inst.
// Block-contiguous split: sub-quarter covers edges [j+8sub, j+8sub+8).
__global__ __launch_bounds__(256) void aggregate_xb(const uint2* __restrict__ xb2,
                                                    const float* __restrict__ x,
                                                    const int* __restrict__ offsets,
                                                    const int* __restrict__ degs,
                                                    const unsigned short* __restrict__ csr,
                                                    const float* __restrict__ dis,
                                                    unsigned int* __restrict__ outb) {
    int wave = threadIdx.x >> 6;
    int lane = threadIdx.x & 63;
    int i = blockIdx.x * 4 + wave;
    if (i >= N_NODES) return;
    int sub = lane >> 4;              // 0..3: which edge-octet
    int q   = lane & 15;              // uint2 index within the 16-uint2 row
    float a0 = 0.f, a1 = 0.f, a2 = 0.f, a3 = 0.f;
    int j = offsets[i];
    int s1 = j + degs[i];
    for (; j + 32 <= s1; j += 32) {   // full chunks: one uint4 csr load
        uint4 w = *(const uint4*)&csr[j + 8 * sub];
        int s[8];
        s[0] = w.x & 0xffff;  s[1] = w.x >> 16;
        s[2] = w.y & 0xffff;  s[3] = w.y >> 16;
        s[4] = w.z & 0xffff;  s[5] = w.z >> 16;
        s[6] = w.w & 0xffff;  s[7] = w.w >> 16;
        uint2 r[8];
#pragma unroll
        for (int u = 0; u < 8; ++u) r[u] = xb2[(size_t)s[u] * 16 + q];
#pragma unroll
        for (int u = 0; u < 8; ++u) {
            a0 += bf16lo(r[u].x);  a1 += bf16hi(r[u].x);
            a2 += bf16lo(r[u].y);  a3 += bf16hi(r[u].y);
        }
    }
    if (j < s1) {                      // masked tail chunk (scalar loads)
        int s[8]; float m[8];
#pragma unroll
        for (int u = 0; u < 8; ++u) {
            int e = j + 4 * u + sub;
            bool valid = e < s1;
            s[u] = valid ? (int)csr[e] : 0;
            m[u] = valid ? 1.f : 0.f;
        }
        uint2 r[8];
#pragma unroll
        for (int u = 0; u < 8; ++u) r[u] = xb2[(size_t)s[u] * 16 + q];
#pragma unroll
        for (int u = 0; u < 8; ++u) {
            a0 += m[u] * bf16lo(r[u].x);  a1 += m[u] * bf16hi(r[u].x);
            a2 += m[u] * bf16lo(r[u].y);  a3 += m[u] * bf16hi(r[u].y);
        }
    }
    a0 += __shfl_xor(a0, 16, 64);  a1 += __shfl_xor(a1, 16, 64);
    a2 += __shfl_xor(a2, 16, 64);  a3 += __shfl_xor(a3, 16, 64);
    a0 += __shfl_xor(a0, 32, 64);  a1 += __shfl_xor(a1, 32, 64);
    a2 += __shfl_xor(a2, 32, 64);  a3 += __shfl_xor(a3, 32, 64);
    float dii = dis[i];
    float d2 = dii * dii;
    float4 sx = ((const float4*)x)[(size_t)i * 16 + q];   // self in fp32
    a0 = dii * a0 + d2 * sx.x;
    a1 = dii * a1 + d2 * sx.y;
    a2 = dii * a2 + d2 * sx.z;
    a3 = dii * a3 + d2 * sx.w;
    if (sub == 0)
        ((uint2*)outb)[(size_t)i * 16 + q] = make_uint2(bf16pair(a0, a1), bf16pair(a2, a3));
}

// ---------------------------------------------------------------------------
// K6: mean-pool over bf16 table (batch sorted -> register-accumulate, flush on change)
__global__ __launch_bounds__(128) void pool16(const unsigned int* __restrict__ hb,
                                              const int* __restrict__ batch,
                                              float* __restrict__ g_acc,
                                              float* __restrict__ g_cnt) {
    const int NB = 16;
    int base = blockIdx.x * NB;
    int f = threadIdx.x;              // feature 0..127
    int uidx = f >> 1;                // uint index within 64-uint row
    bool hi = f & 1;
    float acc = 0.f;
    int cur = -1, cnt = 0;
    for (int n = 0; n < NB; ++n) {
        int i = base + n;
        if (i >= N_NODES) break;
        int b = batch[i];
        if (b != cur) {
            if (cur >= 0) {
                atomicAdd(&g_acc[(size_t)cur * F_HID + f], acc);
                if (f == 0) atomicAdd(&g_cnt[cur], (float)cnt);
            }
            cur = b; acc = 0.f; cnt = 0;
        }
        unsigned int u = hb[(size_t)i * 64 + uidx];
        acc += hi ? bf16hi(u) : bf16lo(u);
        cnt++;
    }
    if (cur >= 0) {
        atomicAdd(&g_acc[(size_t)cur * F_HID + f], acc);
        if (f == 0) atomicAdd(&g_cnt[cur], (float)cnt);
    }
}

// ---------------------------------------------------------------------------
// K7: fused graph head: g2 = (g_acc/cnt)@W2 + b2; g_hid = relu(g2@Wm1+bm1);
// out = g_hid@Wm2 + bm2.  One block per graph, 512 threads.
__global__ __launch_bounds__(512) void fused_mlp(const float* __restrict__ g_acc,
                                                 const float* __restrict__ g_cnt,
                                                 const float* __restrict__ W2,
                                                 const float* __restrict__ b2,
                                                 const float* __restrict__ Wm1,
                                                 const float* __restrict__ bm1,
                                                 const float* __restrict__ Wm2,
                                                 const float* __restrict__ bm2,
                                                 float* __restrict__ out) {
    __shared__ float pool_row[F_HID];
    __shared__ float g2row[F_HID];
    __shared__ float hid[N_HID];
    int g = blockIdx.x;
    int t = threadIdx.x;              // 0..511
    if (t < F_HID) {
        float c = g_cnt[g];
        pool_row[t] = g_acc[(size_t)g * F_HID + t] / fmaxf(c, 1.0f);
    }
    __syncthreads();
    if (t < F_HID) {
        float acc = b2[t];
        for (int k = 0; k < F_HID; ++k) acc += pool_row[k] * W2[(size_t)k * F_HID + t];
        g2row[t] = acc;
    }
    __syncthreads();
    {
        float acc = bm1[t];
        for (int k = 0; k < F_HID; ++k) acc += g2row[k] * Wm1[(size_t)k * N_HID + t];
        hid[t] = fmaxf(acc, 0.f);
    }
    __syncthreads();
    if (t < N_OUT) {
        float acc = bm2[t];
        for (int k = 0; k < N_HID; ++k) acc += hid[k] * Wm2[(size_t)k * N_OUT + t];
        out[(size_t)g * N_OUT + t] = acc;
    }
}

// ---------------------------------------------------------------------------
extern "C" void kernel_launch(void* const* d_in, const int* in_sizes, int n_in,
                              void* d_out, int out_size, void* d_ws, size_t ws_size,
                              hipStream_t stream) {
    const float* x   = (const float*)d_in[0];
    const int* ei    = (const int*)d_in[1];     // [2, E] int32
    const int* batch = (const int*)d_in[2];
    const float* W0 = (const float*)d_in[3];  const float* b0 = (const float*)d_in[4];
    const float* W1 = (const float*)d_in[5];  const float* b1 = (const float*)d_in[6];
    const float* W2 = (const float*)d_in[7];  const float* b2 = (const float*)d_in[8];
    const float* Wm1 = (const float*)d_in[9];  const float* bm1 = (const float*)d_in[10];
    const float* Wm2 = (const float*)d_in[11]; const float* bm2 = (const float*)d_in[12];

    // bump allocator on d_ws, 256B-aligned slots
    char* p = (char*)d_ws;
    auto alloc = [&](size_t bytes) -> char* {
        char* r = p;
        p += (bytes + 255) & ~(size_t)255;
        return r;
    };
    // zero-init region (contiguous in allocation order)
    int*   indeg  = (int*)alloc(N_NODES * 4);
    float* g_acc  = (float*)alloc((size_t)N_GRAPHS * F_HID * 4);
    float* g_cnt  = (float*)alloc(N_GRAPHS * 4);
    size_t zero_bytes = (size_t)(p - (char*)indeg);
    // rest
    int*   blockSums = (int*)alloc(SCAN_NBLK * 4);
    int*   offsets = (int*)alloc((N_NODES + 1) * 4);
    int*   degs    = (int*)alloc(N_NODES * 4);
    float* dis     = (float*)alloc(N_NODES * 4);
    unsigned short* csr = (unsigned short*)alloc((size_t)CSR_CAP * 2 + 32);
    unsigned int* xb     = (unsigned int*)alloc((size_t)N_NODES * F_IN / 2 * 4);   // bf16 x' (dis-scaled)
    unsigned int* axb    = (unsigned int*)alloc((size_t)N_PAD * F_IN / 2 * 4);     // bf16 Âx (plain)
    unsigned int* h_ab   = (unsigned int*)alloc((size_t)N_PAD * F_HID / 2 * 4);    // bf16 h_a (plain)
    unsigned int* h_tmpb = (unsigned int*)alloc((size_t)N_PAD * F_HID / 2 * 4);    // bf16 (dis-scaled)
    unsigned int* h_bb   = (unsigned int*)alloc((size_t)N_NODES * F_HID / 2 * 4);  // bf16 (dis-scaled)
    unsigned int* agg2b  = (unsigned int*)alloc((size_t)N_NODES * F_HID / 2 * 4);  // bf16 (plain)
    unsigned short* W0Tb = (unsigned short*)alloc((size_t)128 * F_IN * 2);
    unsigned short* W1Tb = (unsigned short*)alloc((size_t)128 * F_HID * 2);
    (void)ws_size; (void)in_sizes; (void)n_in; (void)out_size;

    (void)hipMemsetAsync(indeg, 0, zero_bytes, stream);

    count_deg<<<(N_EDGES + 255) / 256, 256, 0, stream>>>(ei, indeg);
    scan_partial<<<SCAN_NBLK, SCAN_B, 0, stream>>>(indeg, blockSums);
    scan_block_sums<<<1, SCAN_B, 0, stream>>>(blockSums);
    scan_final<<<SCAN_NBLK, SCAN_B, 0, stream>>>(indeg, blockSums, offsets, degs, dis);
    build_csr<<<(N_EDGES + 255) / 256, 256, 0, stream>>>(ei, offsets, indeg, csr);
    cvt_bf16<<<(N_NODES * F_IN / 4 + 255) / 256, 256, 0, stream>>>(x, dis, xb, N_NODES * F_IN / 4);
    cvt_wt2<<<((F_IN + F_HID) * 128 + 255) / 256, 256, 0, stream>>>(W0, W0Tb, W1, W1Tb);

    int agg_grid = (N_NODES + 3) / 4;          // 4 nodes (waves) per block
    int mfma_grid = (N_NODES + 63) / 64;       // 782 blocks

    // layer 0 (reordered): axb = bf16(Â x); h_ab = bf16(relu(axb @ W0 + b0))
    aggregate_xb<<<agg_grid, 256, 0, stream>>>((const uint2*)xb, x, offsets, degs, csr, dis, axb);
    gemm_mfma<F_IN, true, false><<<mfma_grid, 256, 0, stream>>>(
        (const unsigned short*)axb, W0Tb, b0, nullptr, h_ab, N_NODES);
    // layer 1: h_tmpb = bf16(dis * (h_ab @ W1)); h_bb = bf16(dis * relu(Â.. + b1))
    gemm_mfma<F_HID, false, true><<<mfma_grid, 256, 0, stream>>>(
        (const unsigned short*)h_ab, W1Tb, nullptr, dis, h_tmpb, N_NODES);
    aggregate128b<true, true, true><<<agg_grid, 256, 0, stream>>>(
        (const uint2*)h_tmpb, offsets, degs, csr, dis, b1, h_bb);
    // layer 2 (commuted): agg2b = bf16(Â h_bb); pool; then @W2 + b2 in fused head
    aggregate128b<false, false, false><<<agg_grid, 256, 0, stream>>>(
        (const uint2*)h_bb, offsets, degs, csr, dis, nullptr, agg2b);

    // pool + fused (W2 + MLP) head
    pool16<<<(N_NODES + 15) / 16, 128, 0, stream>>>(agg2b, batch, g_acc, g_cnt);
    fused_mlp<<<N_GRAPHS, 512, 0, stream>>>(g_acc, g_cnt, W2, b2, Wm1, bm1, Wm2, bm2,
                                            (float*)d_out);
}

// Round 18
// 314.357 us; speedup vs baseline: 1.0714x; 1.0714x over previous
//
#include <hip/hip_runtime.h>
#include <hip/hip_bf16.h>
#include <math.h>
#include <stdint.h>

#define N_NODES 50000
#define N_PAD   50048   // padded rows for MFMA tile overrun
#define N_EDGES 800000
#define N_GRAPHS 256
#define F_IN 64
#define F_HID 128
#define N_HID 512
#define N_OUT 256
#define CSR_CAP (N_EDGES + 8 * N_NODES)   // aligned-start padding headroom

#define NBKT   49            // buckets of 1024 nodes (dst >> 10)
#define BKT_S  24576         // per-bucket capacity (expected ~16.4k, 65 sigma pad)
#define EPB    3328          // edges per bin_edges block (13 * 256)
#define NBIN_BLK ((N_EDGES + EPB - 1) / EPB)   // 241

using bf16x8 = __attribute__((ext_vector_type(8))) short;   // MFMA A/B frag (4 VGPRs)
using f32x4  = __attribute__((ext_vector_type(4))) float;   // MFMA C/D frag

// pack two fp32 into a uint holding two bf16 (RNE); low16 = a, high16 = b
__device__ __forceinline__ unsigned int bf16pair(float a, float b) {
    unsigned int ua = __float_as_uint(a);
    unsigned int ub = __float_as_uint(b);
    ua += 0x7fffu + ((ua >> 16) & 1u);
    ub += 0x7fffu + ((ub >> 16) & 1u);
    return (ua >> 16) | (ub & 0xffff0000u);
}
__device__ __forceinline__ float bf16lo(unsigned int u) { return __uint_as_float(u << 16); }
__device__ __forceinline__ float bf16hi(unsigned int u) { return __uint_as_float(u & 0xffff0000u); }

// ---------------------------------------------------------------------------
// K0: xb'[s] = bf16(dis[s] * x[s])  (pre-scaled gather table)
__global__ void cvt_bf16(const float* __restrict__ in, const float* __restrict__ dis,
                         unsigned int* __restrict__ out, int n4) {
    int idx = blockIdx.x * blockDim.x + threadIdx.x;
    if (idx < n4) {
        int node = idx >> 4;                  // 16 float4 per 64-f row
        float d = dis[node];
        float4 v = ((const float4*)in)[idx];
        ((uint2*)out)[idx] = make_uint2(bf16pair(d * v.x, d * v.y),
                                        bf16pair(d * v.z, d * v.w));
    }
}

// K0b: both weight tables fp32 [K][128] -> bf16 [128][K] in one dispatch
__global__ void cvt_wt2(const float* __restrict__ W0, unsigned short* __restrict__ W0Tb,
                        const float* __restrict__ W1, unsigned short* __restrict__ W1Tb) {
    int idx = blockIdx.x * blockDim.x + threadIdx.x;
    const int N0 = F_IN * 128;
    const int N1 = F_HID * 128;
    if (idx < N0) {
        int k = idx >> 7, n = idx & 127;
        unsigned int u = __float_as_uint(W0[idx]);
        u += 0x7fffu + ((u >> 16) & 1u);
        W0Tb[n * F_IN + k] = (unsigned short)(u >> 16);
    } else if (idx < N0 + N1) {
        int j = idx - N0;
        int k = j >> 7, n = j & 127;
        unsigned int u = __float_as_uint(W1[j]);
        u += 0x7fffu + ((u >> 16) & 1u);
        W1Tb[n * F_HID + k] = (unsigned short)(u >> 16);
    }
}

// ---------------------------------------------------------------------------
// K1: bin edges by dst>>10 through LDS staging (privatized binning).
// Packed entry: (bucket<<26) | (src<<10) | (dst & 1023) — bucket stripped on
// copy-out. One global atomicAdd per (block,bucket); bulk copy-out coalesced.
__global__ __launch_bounds__(256) void bin_edges(const int* __restrict__ ei,
                                                 int* __restrict__ bucketCur,
                                                 unsigned int* __restrict__ binned) {
    __shared__ int hist[NBKT];
    __shared__ int lbase[NBKT];
    __shared__ int lcur[NBKT];
    __shared__ int gbase[NBKT];
    __shared__ unsigned int staging[EPB];
    int tid = threadIdx.x;
    int base = blockIdx.x * EPB;
    int cnt = N_EDGES - base; if (cnt > EPB) cnt = EPB;
    if (tid < NBKT) hist[tid] = 0;
    __syncthreads();
    unsigned int pk[13]; int nk = 0;
#pragma unroll
    for (int u = 0; u < 13; ++u) {
        int e = base + u * 256 + tid;
        if (u * 256 + tid < cnt) {
            unsigned int s = (unsigned int)ei[e];
            unsigned int d = (unsigned int)ei[N_EDGES + e];
            unsigned int b = d >> 10;
            pk[nk++] = (b << 26) | (s << 10) | (d & 1023u);
        }
    }
    for (int u = 0; u < nk; ++u) atomicAdd(&hist[pk[u] >> 26], 1);
    __syncthreads();
    if (tid == 0) {                      // tiny serial scan over 49 buckets
        int acc = 0;
        for (int b = 0; b < NBKT; ++b) { lbase[b] = acc; lcur[b] = acc; acc += hist[b]; }
    }
    __syncthreads();
    for (int u = 0; u < nk; ++u) {
        int pos = atomicAdd(&lcur[pk[u] >> 26], 1);
        staging[pos] = pk[u];
    }
    if (tid < NBKT && hist[tid] > 0)
        gbase[tid] = atomicAdd(&bucketCur[tid], hist[tid]);
    __syncthreads();
    for (int k = tid; k < cnt; k += 256) {
        unsigned int v = staging[k];
        int b = v >> 26;
        binned[(size_t)b * BKT_S + gbase[b] + (k - lbase[b])] = v & 0x3ffffffu;
    }
}

// K2a: per-bucket degree histogram -> degs, dis, aligned local offsets.
__global__ __launch_bounds__(256) void bucket_deg(const unsigned int* __restrict__ binned,
                                                  const int* __restrict__ bucketCur,
                                                  int* __restrict__ degs,
                                                  float* __restrict__ dis,
                                                  int* __restrict__ localOff,
                                                  int* __restrict__ bucketAligned) {
    __shared__ int hist[1024];
    __shared__ int tsum[256];
    int b = blockIdx.x;
    int tid = threadIdx.x;
    int node0 = b << 10;
    for (int k = tid; k < 1024; k += 256) hist[k] = 0;
    __syncthreads();
    int cnt = bucketCur[b];
    for (int k = tid; k < cnt; k += 256)
        atomicAdd(&hist[binned[(size_t)b * BKT_S + k] & 1023u], 1);
    __syncthreads();
    int base4 = tid * 4;
    int a[4]; int s = 0;
#pragma unroll
    for (int j = 0; j < 4; ++j) {
        int d = hist[base4 + j];
        a[j] = s;
        s += (d + 7) & ~7;
    }
    tsum[tid] = s;
    __syncthreads();
    for (int off = 1; off < 256; off <<= 1) {
        int t = (tid >= off) ? tsum[tid - off] : 0;
        __syncthreads();
        tsum[tid] += t;
        __syncthreads();
    }
    int excl = tsum[tid] - s;
#pragma unroll
    for (int j = 0; j < 4; ++j) {
        int node = node0 + base4 + j;
        if (node < N_NODES) {
            int d = hist[base4 + j];
            degs[node] = d;
            dis[node] = rsqrtf((float)(d + 1));
            localOff[node] = excl + a[j];
        }
    }
    if (tid == 255) bucketAligned[b] = tsum[255];
}

// K2b: tiny scan of per-bucket aligned totals -> csrBase
__global__ void csr_base_scan(const int* __restrict__ bucketAligned,
                              int* __restrict__ csrBase) {
    if (threadIdx.x == 0) {
        int acc = 0;
        for (int b = 0; b < NBKT; ++b) { csrBase[b] = acc; acc += bucketAligned[b]; }
    }
}

// K2c: per-bucket CSR scatter (single block owns the bucket region -> writes
// stay in one XCD's L2, no line bouncing) + global offsets write.
__global__ __launch_bounds__(256) void scatter_local(const unsigned int* __restrict__ binned,
                                                     const int* __restrict__ bucketCur,
                                                     const int* __restrict__ csrBase,
                                                     const int* __restrict__ localOff,
                                                     int* __restrict__ offsets,
                                                     unsigned short* __restrict__ csr) {
    __shared__ int lcur[1024];
    int b = blockIdx.x;
    int tid = threadIdx.x;
    int node0 = b << 10;
    int csrB = csrBase[b];
    for (int k = tid; k < 1024; k += 256) {
        int node = node0 + k;
        int lo = (node < N_NODES) ? localOff[node] : 0;
        lcur[k] = lo;
        if (node < N_NODES) offsets[node] = csrB + lo;
    }
    __syncthreads();
    int cnt = bucketCur[b];
    for (int k = tid; k < cnt; k += 256) {
        unsigned int v = binned[(size_t)b * BKT_S + k];
        int dl = v & 1023u;
        int src = v >> 10;
        int p = atomicAdd(&lcur[dl], 1);
        csr[csrB + p] = (unsigned short)src;
    }
}

// ---------------------------------------------------------------------------
// K4: MFMA GEMM. C[M,128] = A[M,K]@W[K,128], A bf16 [M][K], WT bf16 [128][K].
template <int K, bool BIASRELU, bool DISSCALE>
__global__ __launch_bounds__(256) void gemm_mfma(const unsigned short* __restrict__ Ab,
                                                 const unsigned short* __restrict__ WTb,
                                                 const float* __restrict__ bias,
                                                 const float* __restrict__ disv,
                                                 unsigned int* __restrict__ outb, int M) {
    int wv = threadIdx.x >> 6;
    int lane = threadIdx.x & 63;
    int m = lane & 15;
    int quad = lane >> 4;
    int row0 = blockIdx.x * 64 + wv * 16;
    f32x4 acc[8];
#pragma unroll
    for (int t = 0; t < 8; ++t) acc[t] = (f32x4){0.f, 0.f, 0.f, 0.f};
#pragma unroll
    for (int ks = 0; ks < K; ks += 32) {
        bf16x8 af = *(const bf16x8*)&Ab[(size_t)(row0 + m) * K + ks + quad * 8];
#pragma unroll
        for (int t = 0; t < 8; ++t) {
            bf16x8 bf = *(const bf16x8*)&WTb[(size_t)(t * 16 + m) * K + ks + quad * 8];
            acc[t] = __builtin_amdgcn_mfma_f32_16x16x32_bf16(af, bf, acc[t], 0, 0, 0);
        }
    }
    float dr[4];
#pragma unroll
    for (int r = 0; r < 4; ++r) {
        int row = row0 + quad * 4 + r;
        dr[r] = DISSCALE ? ((row < M) ? disv[row] : 0.f) : 1.f;
    }
#pragma unroll
    for (int t = 0; t < 8; ++t) {
        int col = t * 16 + m;
        float bcol = 0.f;
        if (BIASRELU) bcol = bias[col];
#pragma unroll
        for (int r = 0; r < 4; ++r) {
            float v = acc[t][r];
            if (BIASRELU) v = fmaxf(v + bcol, 0.f);
            if (DISSCALE) v = v * dr[r];
            float vn = __shfl_xor(v, 1, 64);    // neighbor col's value
            if ((m & 1) == 0) {
                int row = row0 + quad * 4 + r;
                if (row < M)
                    outb[(size_t)row * 64 + (col >> 1)] = bf16pair(v, vn);
            }
        }
    }
}

// ---------------------------------------------------------------------------
// K5a: F=128 aggregate over PRE-SCALED bf16 table. uint2 lanes, 2 edges/inst;
// uint4 csr loads on aligned full chunks; masked tail.
template <bool RELU, bool BIAS, bool SCALEOUT>
__global__ __launch_bounds__(256) void aggregate128b(const uint2* __restrict__ hb2,
                                                     const int* __restrict__ offsets,
                                                     const int* __restrict__ degs,
                                                     const unsigned short* __restrict__ csr,
                                                     const float* __restrict__ dis,
                                                     const float* __restrict__ bias,
                                                     unsigned int* __restrict__ outb) {
    int wave = threadIdx.x >> 6;
    int lane = threadIdx.x & 63;
    int i = blockIdx.x * 4 + wave;
    if (i >= N_NODES) return;
    int sub = lane >> 5;
    int q   = lane & 31;
    float a0 = 0.f, a1 = 0.f, a2 = 0.f, a3 = 0.f;
    int j = offsets[i];
    int s1 = j + degs[i];
    for (; j + 16 <= s1; j += 16) {       // full chunks: one uint4 csr load
        uint4 w = *(const uint4*)&csr[j + 8 * sub];
        int s[8];
        s[0] = w.x & 0xffff;  s[1] = w.x >> 16;
        s[2] = w.y & 0xffff;  s[3] = w.y >> 16;
        s[4] = w.z & 0xffff;  s[5] = w.z >> 16;
        s[6] = w.w & 0xffff;  s[7] = w.w >> 16;
        uint2 r[8];
#pragma unroll
        for (int u = 0; u < 8; ++u) r[u] = hb2[(size_t)s[u] * 32 + q];
#pragma unroll
        for (int u = 0; u < 8; ++u) {
            a0 += bf16lo(r[u].x);  a1 += bf16hi(r[u].x);
            a2 += bf16lo(r[u].y);  a3 += bf16hi(r[u].y);
        }
    }
    if (j < s1) {                          // masked tail chunk (scalar loads)
        int s[8]; float m[8];
#pragma unroll
        for (int u = 0; u < 8; ++u) {
            int e = j + 2 * u + sub;
            bool valid = e < s1;
            s[u] = valid ? (int)csr[e] : 0;
            m[u] = valid ? 1.f : 0.f;
        }
        uint2 r[8];
#pragma unroll
        for (int u = 0; u < 8; ++u) r[u] = hb2[(size_t)s[u] * 32 + q];
#pragma unroll
        for (int u = 0; u < 8; ++u) {
            a0 += m[u] * bf16lo(r[u].x);  a1 += m[u] * bf16hi(r[u].x);
            a2 += m[u] * bf16lo(r[u].y);  a3 += m[u] * bf16hi(r[u].y);
        }
    }
    a0 += __shfl_xor(a0, 32, 64);
    a1 += __shfl_xor(a1, 32, 64);
    a2 += __shfl_xor(a2, 32, 64);
    a3 += __shfl_xor(a3, 32, 64);
    uint2 su = hb2[(size_t)i * 32 + q];     // self: weight 1 in scaled domain
    a0 += bf16lo(su.x);  a1 += bf16hi(su.x);
    a2 += bf16lo(su.y);  a3 += bf16hi(su.y);
    float dii = dis[i];
    a0 *= dii; a1 *= dii; a2 *= dii; a3 *= dii;
    if (BIAS) {
        float4 b = ((const float4*)bias)[q];
        a0 += b.x; a1 += b.y; a2 += b.z; a3 += b.w;
    }
    if (RELU) {
        a0 = fmaxf(a0, 0.f); a1 = fmaxf(a1, 0.f);
        a2 = fmaxf(a2, 0.f); a3 = fmaxf(a3, 0.f);
    }
    if (sub == 0) {
        float sc = SCALEOUT ? dii : 1.f;
        ((uint2*)outb)[(size_t)i * 32 + q] =
            make_uint2(bf16pair(sc * a0, sc * a1), bf16pair(sc * a2, sc * a3));
    }
}

// K5b: F=64 aggregate over pre-scaled bf16 x-table. uint2 lanes, 4 edges/inst.
__global__ __launch_bounds__(256) void aggregate_xb(const uint2* __restrict__ xb2,
                                                    const float* __restrict__ x,
                                                    const int* __restrict__ offsets,
                                                    const int* __restrict__ degs,
                                                    const unsigned short* __restrict__ csr,
                                                    const float* __restrict__ dis,
                                                    unsigned int* __restrict__ outb) {
    int wave = threadIdx.x >> 6;
    int lane = threadIdx.x & 63;
    int i = blockIdx.x * 4 + wave;
    if (i >= N_NODES) return;
    int sub = lane >> 4;              // 0..3: which edge-octet
    int q   = lane & 15;              // uint2 index within the 16-uint2 row
    float a0 = 0.f, a1 = 0.f, a2 = 0.f, a3 = 0.f;
    int j = offsets[i];
    int s1 = j + degs[i];
    for (; j + 32 <= s1; j += 32) {   // full chunks: one uint4 csr load
        uint4 w = *(const uint4*)&csr[j + 8 * sub];
        int s[8];
        s[0] = w.x & 0xffff;  s[1] = w.x >> 16;
        s[2] = w.y & 0xffff;  s[3] = w.y >> 16;
        s[4] = w.z & 0xffff;  s[5] = w.z >> 16;
        s[6] = w.w & 0xffff;  s[7] = w.w >> 16;
        uint2 r[8];
#pragma unroll
        for (int u = 0; u < 8; ++u) r[u] = xb2[(size_t)s[u] * 16 + q];
#pragma unroll
        for (int u = 0; u < 8; ++u) {
            a0 += bf16lo(r[u].x);  a1 += bf16hi(r[u].x);
            a2 += bf16lo(r[u].y);  a3 += bf16hi(r[u].y);
        }
    }
    if (j < s1) {                      // masked tail chunk (scalar loads)
        int s[8]; float m[8];
#pragma unroll
        for (int u = 0; u < 8; ++u) {
            int e = j + 4 * u + sub;
            bool valid = e < s1;
            s[u] = valid ? (int)csr[e] : 0;
            m[u] = valid ? 1.f : 0.f;
        }
        uint2 r[8];
#pragma unroll
        for (int u = 0; u < 8; ++u) r[u] = xb2[(size_t)s[u] * 16 + q];
#pragma unroll
        for (int u = 0; u < 8; ++u) {
            a0 += m[u] * bf16lo(r[u].x);  a1 += m[u] * bf16hi(r[u].x);
            a2 += m[u] * bf16lo(r[u].y);  a3 += m[u] * bf16hi(r[u].y);
        }
    }
    a0 += __shfl_xor(a0, 16, 64);  a1 += __shfl_xor(a1, 16, 64);
    a2 += __shfl_xor(a2, 16, 64);  a3 += __shfl_xor(a3, 16, 64);
    a0 += __shfl_xor(a0, 32, 64);  a1 += __shfl_xor(a1, 32, 64);
    a2 += __shfl_xor(a2, 32, 64);  a3 += __shfl_xor(a3, 32, 64);
    float dii = dis[i];
    float d2 = dii * dii;
    float4 sx = ((const float4*)x)[(size_t)i * 16 + q];   // self in fp32
    a0 = dii * a0 + d2 * sx.x;
    a1 = dii * a1 + d2 * sx.y;
    a2 = dii * a2 + d2 * sx.z;
    a3 = dii * a3 + d2 * sx.w;
    if (sub == 0)
        ((uint2*)outb)[(size_t)i * 16 + q] = make_uint2(bf16pair(a0, a1), bf16pair(a2, a3));
}

// ---------------------------------------------------------------------------
// K6: mean-pool over bf16 table (batch sorted -> register-accumulate, flush on change)
__global__ __launch_bounds__(128) void pool16(const unsigned int* __restrict__ hb,
                                              const int* __restrict__ batch,
                                              float* __restrict__ g_acc,
                                              float* __restrict__ g_cnt) {
    const int NB = 16;
    int base = blockIdx.x * NB;
    int f = threadIdx.x;              // feature 0..127
    int uidx = f >> 1;                // uint index within 64-uint row
    bool hi = f & 1;
    float acc = 0.f;
    int cur = -1, cnt = 0;
    for (int n = 0; n < NB; ++n) {
        int i = base + n;
        if (i >= N_NODES) break;
        int b = batch[i];
        if (b != cur) {
            if (cur >= 0) {
                atomicAdd(&g_acc[(size_t)cur * F_HID + f], acc);
                if (f == 0) atomicAdd(&g_cnt[cur], (float)cnt);
            }
            cur = b; acc = 0.f; cnt = 0;
        }
        unsigned int u = hb[(size_t)i * 64 + uidx];
        acc += hi ? bf16hi(u) : bf16lo(u);
        cnt++;
    }
    if (cur >= 0) {
        atomicAdd(&g_acc[(size_t)cur * F_HID + f], acc);
        if (f == 0) atomicAdd(&g_cnt[cur], (float)cnt);
    }
}

// ---------------------------------------------------------------------------
// K7: fused graph head: g2 = (g_acc/cnt)@W2 + b2; g_hid = relu(g2@Wm1+bm1);
// out = g_hid@Wm2 + bm2.  One block per graph, 512 threads.
__global__ __launch_bounds__(512) void fused_mlp(const float* __restrict__ g_acc,
                                                 const float* __restrict__ g_cnt,
                                                 const float* __restrict__ W2,
                                                 const float* __restrict__ b2,
                                                 const float* __restrict__ Wm1,
                                                 const float* __restrict__ bm1,
                                                 const float* __restrict__ Wm2,
                                                 const float* __restrict__ bm2,
                                                 float* __restrict__ out) {
    __shared__ float pool_row[F_HID];
    __shared__ float g2row[F_HID];
    __shared__ float hid[N_HID];
    int g = blockIdx.x;
    int t = threadIdx.x;              // 0..511
    if (t < F_HID) {
        float c = g_cnt[g];
        pool_row[t] = g_acc[(size_t)g * F_HID + t] / fmaxf(c, 1.0f);
    }
    __syncthreads();
    if (t < F_HID) {
        float acc = b2[t];
        for (int k = 0; k < F_HID; ++k) acc += pool_row[k] * W2[(size_t)k * F_HID + t];
        g2row[t] = acc;
    }
    __syncthreads();
    {
        float acc = bm1[t];
        for (int k = 0; k < F_HID; ++k) acc += g2row[k] * Wm1[(size_t)k * N_HID + t];
        hid[t] = fmaxf(acc, 0.f);
    }
    __syncthreads();
    if (t < N_OUT) {
        float acc = bm2[t];
        for (int k = 0; k < N_HID; ++k) acc += hid[k] * Wm2[(size_t)k * N_OUT + t];
        out[(size_t)g * N_OUT + t] = acc;
    }
}

// ---------------------------------------------------------------------------
extern "C" void kernel_launch(void* const* d_in, const int* in_sizes, int n_in,
                              void* d_out, int out_size, void* d_ws, size_t ws_size,
                              hipStream_t stream) {
    const float* x   = (const float*)d_in[0];
    const int* ei    = (const int*)d_in[1];     // [2, E] int32
    const int* batch = (const int*)d_in[2];
    const float* W0 = (const float*)d_in[3];  const float* b0 = (const float*)d_in[4];
    const float* W1 = (const float*)d_in[5];  const float* b1 = (const float*)d_in[6];
    const float* W2 = (const float*)d_in[7];  const float* b2 = (const float*)d_in[8];
    const float* Wm1 = (const float*)d_in[9];  const float* bm1 = (const float*)d_in[10];
    const float* Wm2 = (const float*)d_in[11]; const float* bm2 = (const float*)d_in[12];

    // bump allocator on d_ws, 256B-aligned slots
    char* p = (char*)d_ws;
    auto alloc = [&](size_t bytes) -> char* {
        char* r = p;
        p += (bytes + 255) & ~(size_t)255;
        return r;
    };
    // zero-init region (contiguous in allocation order)
    int*   bucketCur = (int*)alloc(NBKT * 4);
    float* g_acc  = (float*)alloc((size_t)N_GRAPHS * F_HID * 4);
    float* g_cnt  = (float*)alloc(N_GRAPHS * 4);
    size_t zero_bytes = (size_t)(p - (char*)bucketCur);
    // rest
    unsigned int* binned = (unsigned int*)alloc((size_t)NBKT * BKT_S * 4);
    int*   bucketAligned = (int*)alloc(NBKT * 4);
    int*   csrBase = (int*)alloc(NBKT * 4);
    int*   offsets = (int*)alloc((size_t)N_NODES * 4);
    int*   degs    = (int*)alloc((size_t)N_NODES * 4);
    int*   localOff = (int*)alloc((size_t)N_NODES * 4);
    float* dis     = (float*)alloc((size_t)N_NODES * 4);
    unsigned short* csr = (unsigned short*)alloc((size_t)CSR_CAP * 2 + 32);
    unsigned int* xb     = (unsigned int*)alloc((size_t)N_NODES * F_IN / 2 * 4);   // bf16 x' (dis-scaled)
    unsigned int* axb    = (unsigned int*)alloc((size_t)N_PAD * F_IN / 2 * 4);     // bf16 Âx (plain)
    unsigned int* h_ab   = (unsigned int*)alloc((size_t)N_PAD * F_HID / 2 * 4);    // bf16 h_a (plain)
    unsigned int* h_tmpb = (unsigned int*)alloc((size_t)N_PAD * F_HID / 2 * 4);    // bf16 (dis-scaled)
    unsigned int* h_bb   = (unsigned int*)alloc((size_t)N_NODES * F_HID / 2 * 4);  // bf16 (dis-scaled)
    unsigned int* agg2b  = (unsigned int*)alloc((size_t)N_NODES * F_HID / 2 * 4);  // bf16 (plain)
    unsigned short* W0Tb = (unsigned short*)alloc((size_t)128 * F_IN * 2);
    unsigned short* W1Tb = (unsigned short*)alloc((size_t)128 * F_HID * 2);
    (void)ws_size; (void)in_sizes; (void)n_in; (void)out_size;

    (void)hipMemsetAsync(bucketCur, 0, zero_bytes, stream);

    // CSR construction: privatized binning -> per-bucket local CSR
    bin_edges<<<NBIN_BLK, 256, 0, stream>>>(ei, bucketCur, binned);
    bucket_deg<<<NBKT, 256, 0, stream>>>(binned, bucketCur, degs, dis, localOff, bucketAligned);
    csr_base_scan<<<1, 64, 0, stream>>>(bucketAligned, csrBase);
    scatter_local<<<NBKT, 256, 0, stream>>>(binned, bucketCur, csrBase, localOff, offsets, csr);

    cvt_bf16<<<(N_NODES * F_IN / 4 + 255) / 256, 256, 0, stream>>>(x, dis, xb, N_NODES * F_IN / 4);
    cvt_wt2<<<((F_IN + F_HID) * 128 + 255) / 256, 256, 0, stream>>>(W0, W0Tb, W1, W1Tb);

    int agg_grid = (N_NODES + 3) / 4;          // 4 nodes (waves) per block
    int mfma_grid = (N_NODES + 63) / 64;       // 782 blocks

    // layer 0 (reordered): axb = bf16(Â x); h_ab = bf16(relu(axb @ W0 + b0))
    aggregate_xb<<<agg_grid, 256, 0, stream>>>((const uint2*)xb, x, offsets, degs, csr, dis, axb);
    gemm_mfma<F_IN, true, false><<<mfma_grid, 256, 0, stream>>>(
        (const unsigned short*)axb, W0Tb, b0, nullptr, h_ab, N_NODES);
    // layer 1: h_tmpb = bf16(dis * (h_ab @ W1)); h_bb = bf16(dis * relu(Â.. + b1))
    gemm_mfma<F_HID, false, true><<<mfma_grid, 256, 0, stream>>>(
        (const unsigned short*)h_ab, W1Tb, nullptr, dis, h_tmpb, N_NODES);
    aggregate128b<true, true, true><<<agg_grid, 256, 0, stream>>>(
        (const uint2*)h_tmpb, offsets, degs, csr, dis, b1, h_bb);
    // layer 2 (commuted): agg2b = bf16(Â h_bb); pool; then @W2 + b2 in fused head
    aggregate128b<false, false, false><<<agg_grid, 256, 0, stream>>>(
        (const uint2*)h_bb, offsets, degs, csr, dis, nullptr, agg2b);

    // pool + fused (W2 + MLP) head
    pool16<<<(N_NODES + 15) / 16, 128, 0, stream>>>(agg2b, batch, g_acc, g_cnt);
    fused_mlp<<<N_GRAPHS, 512, 0, stream>>>(g_acc, g_cnt, W2, b2, Wm1, bm1, Wm2, bm2,
                                            (float*)d_out);
}